// Round 1
// baseline (135.200 us; speedup 1.0000x reference)
//
#include <hip/hip_runtime.h>

#define N_EDGES 4096
#define HIDDEN  256
#define EDGE_DIM 128
#define NUM_HEADS 4
#define NUM_GRAPHS 64
#define DH 64   // head dim

typedef __attribute__((ext_vector_type(8))) short short8;
typedef __attribute__((ext_vector_type(4))) float f32x4;

__device__ __forceinline__ unsigned short f2bf(float f) {
  unsigned u = __builtin_bit_cast(unsigned, f);
  u += 0x7FFF + ((u >> 16) & 1);          // RNE
  return (unsigned short)(u >> 16);
}
__device__ __forceinline__ float bf2f(unsigned short u) {
  return __builtin_bit_cast(float, (unsigned)u << 16);
}
__device__ __forceinline__ short8 cvt8(float4 x, float4 y) {
  short8 v;
  v[0] = (short)f2bf(x.x); v[1] = (short)f2bf(x.y);
  v[2] = (short)f2bf(x.z); v[3] = (short)f2bf(x.w);
  v[4] = (short)f2bf(y.x); v[5] = (short)f2bf(y.y);
  v[6] = (short)f2bf(y.z); v[7] = (short)f2bf(y.w);
  return v;
}
__device__ __forceinline__ float4 us4f(ushort4 v) {
  float4 f;
  f.x = bf2f(v.x); f.y = bf2f(v.y); f.z = bf2f(v.z); f.w = bf2f(v.w);
  return f;
}

__device__ __forceinline__ int lbound(const int* __restrict__ a, int n, int v) {
  int lo = 0, hi = n;
  while (lo < hi) { int mid = (lo + hi) >> 1; if (a[mid] < v) lo = mid + 1; else hi = mid; }
  return lo;
}

// MFMA GEMM core: 64x64 tile/block, 256 thr = 4 waves. A fp32; W fp32; N=256.
// C = bf16(acc + bias).  (Used for the Q projection.)
__device__ __forceinline__ void gemm_core(const float* Ap, const float* W,
                                          const float* bias, unsigned short* Cp,
                                          const int K) {
  const int t = threadIdx.x;
  const int m0 = blockIdx.x * 64, n0 = blockIdx.y * 64;
  __shared__ unsigned short As[64 * 40];
  __shared__ unsigned short Ws[64 * 40];
  const int r = t >> 2, kg = t & 3;
  const int lane = t & 63, w = t >> 6;
  const int quad = lane >> 4, l16 = lane & 15;
  const int wm = (w >> 1) * 32, wn = (w & 1) * 32;
  f32x4 acc[2][2] = {};
  const float* pw = W + (size_t)(n0 + r) * K + kg * 8;
  float4 w0 = *(const float4*)(pw), w1 = *(const float4*)(pw + 4);
  const float* pa32 = Ap + (size_t)(m0 + r) * K + kg * 8;
  float4 a0 = *(const float4*)pa32, a1 = *(const float4*)(pa32 + 4);
  for (int kc = 0; kc < K; kc += 32) {
    float4 na0, na1, nw0, nw1;
    if (kc + 32 < K) {
      na0 = *(const float4*)(pa32 + kc + 32); na1 = *(const float4*)(pa32 + kc + 36);
      nw0 = *(const float4*)(pw + kc + 32);   nw1 = *(const float4*)(pw + kc + 36);
    }
    __syncthreads();
    *(short8*)&As[r * 40 + kg * 8] = cvt8(a0, a1);
    *(short8*)&Ws[r * 40 + kg * 8] = cvt8(w0, w1);
    __syncthreads();
    short8 af0 = *(const short8*)&As[(wm + l16) * 40 + quad * 8];
    short8 af1 = *(const short8*)&As[(wm + 16 + l16) * 40 + quad * 8];
    short8 bf0 = *(const short8*)&Ws[(wn + l16) * 40 + quad * 8];
    short8 bf1 = *(const short8*)&Ws[(wn + 16 + l16) * 40 + quad * 8];
    acc[0][0] = __builtin_amdgcn_mfma_f32_16x16x32_bf16(af0, bf0, acc[0][0], 0, 0, 0);
    acc[0][1] = __builtin_amdgcn_mfma_f32_16x16x32_bf16(af0, bf1, acc[0][1], 0, 0, 0);
    acc[1][0] = __builtin_amdgcn_mfma_f32_16x16x32_bf16(af1, bf0, acc[1][0], 0, 0, 0);
    acc[1][1] = __builtin_amdgcn_mfma_f32_16x16x32_bf16(af1, bf1, acc[1][1], 0, 0, 0);
    a0 = na0; a1 = na1; w0 = nw0; w1 = nw1;
  }
#pragma unroll
  for (int j = 0; j < 2; ++j) {
    const int col = n0 + wn + j * 16 + l16;
    const float bj = bias[col];
#pragma unroll
    for (int i = 0; i < 2; ++i) {
#pragma unroll
      for (int reg = 0; reg < 4; ++reg) {
        const int row = m0 + wm + i * 16 + quad * 4 + reg;
        Cp[(size_t)row * HIDDEN + col] = f2bf(acc[i][j][reg] + bj);
      }
    }
  }
}

// Fused edge_proj + in_proj for K/V:
//   C[m0:m0+64, n0:n0+64] = bf16( A @ (Wp @ w_edge)^T + (Wp @ b_edge + bp) )
// A: fp32 [4096 x 128]; Wp: fp32 [256 x 256] (wk or wv slice of w_in).
// Phase A builds the 64x128 fused-weight slice via MFMA (w_edge transpose-staged),
// then the main K=128 GEMM reads B-fragments straight from LDS.
__device__ __forceinline__ void fused_kv_core(const float* __restrict__ A,
                                              const float* __restrict__ Wp,
                                              const float* __restrict__ bp,
                                              const float* __restrict__ w_edge,
                                              const float* __restrict__ b_edge,
                                              unsigned short* __restrict__ C) {
  const int t = threadIdx.x;
  const int m0 = blockIdx.x * 64, n0 = blockIdx.y * 64;
  __shared__ unsigned short As2[64 * 40];
  __shared__ unsigned short Bs2[64 * 40];
  __shared__ unsigned short WfS[64][136];   // fused weight slice, bf16, padded
  __shared__ float bfS[64];                 // fused bias slice
  const int r = t >> 2, kg = t & 3;
  const int lane = t & 63, w = t >> 6;
  const int quad = lane >> 4, l16 = lane & 15;
  const int wm = (w >> 1) * 32, wn = (w & 1) * 32;

  // fused bias: bfS[n] = dot(Wp[n0+n,:], b_edge) + bp[n0+n]
  {
    float s = 0.f;
    const float* wrow = Wp + (size_t)(n0 + r) * HIDDEN + kg * 64;
    const float* be = b_edge + kg * 64;
#pragma unroll
    for (int j = 0; j < 64; j += 4) {
      float4 a = *(const float4*)(wrow + j);
      float4 b = *(const float4*)(be + j);
      s += a.x * b.x + a.y * b.y + a.z * b.z + a.w * b.w;
    }
    s += __shfl_xor(s, 1); s += __shfl_xor(s, 2);
    if (kg == 0) bfS[r] = s + bp[n0 + r];
  }

  // Phase A: WfS[n][k] = bf16( sum_j Wp[n0+n, j] * w_edge[j, k] ), k in [0,128)
#pragma unroll
  for (int kt = 0; kt < 2; ++kt) {
    f32x4 facc[2][2] = {};
    for (int j0 = 0; j0 < HIDDEN; j0 += 32) {
      __syncthreads();
      {  // stage A' = Wp rows (n-major)
        const float* p = Wp + (size_t)(n0 + r) * HIDDEN + j0 + kg * 8;
        float4 a0 = *(const float4*)p, a1 = *(const float4*)(p + 4);
        *(short8*)&As2[r * 40 + kg * 8] = cvt8(a0, a1);
      }
      {  // stage B' = w_edge^T : Bs2[k][j] = w_edge[j0+j][kt*64+k]
        const int j = t >> 3, k8 = (t & 7) * 8;
        const float* p = w_edge + (size_t)(j0 + j) * EDGE_DIM + kt * 64 + k8;
        float4 b0 = *(const float4*)p, b1 = *(const float4*)(p + 4);
        float bb[8] = {b0.x, b0.y, b0.z, b0.w, b1.x, b1.y, b1.z, b1.w};
#pragma unroll
        for (int i = 0; i < 8; ++i) Bs2[(k8 + i) * 40 + j] = f2bf(bb[i]);
      }
      __syncthreads();
      short8 af0 = *(const short8*)&As2[(wm + l16) * 40 + quad * 8];
      short8 af1 = *(const short8*)&As2[(wm + 16 + l16) * 40 + quad * 8];
      short8 bf0 = *(const short8*)&Bs2[(wn + l16) * 40 + quad * 8];
      short8 bf1 = *(const short8*)&Bs2[(wn + 16 + l16) * 40 + quad * 8];
      facc[0][0] = __builtin_amdgcn_mfma_f32_16x16x32_bf16(af0, bf0, facc[0][0], 0, 0, 0);
      facc[0][1] = __builtin_amdgcn_mfma_f32_16x16x32_bf16(af0, bf1, facc[0][1], 0, 0, 0);
      facc[1][0] = __builtin_amdgcn_mfma_f32_16x16x32_bf16(af1, bf0, facc[1][0], 0, 0, 0);
      facc[1][1] = __builtin_amdgcn_mfma_f32_16x16x32_bf16(af1, bf1, facc[1][1], 0, 0, 0);
    }
#pragma unroll
    for (int jj = 0; jj < 2; ++jj)
#pragma unroll
      for (int ii = 0; ii < 2; ++ii)
#pragma unroll
        for (int reg = 0; reg < 4; ++reg) {
          const int n = wm + ii * 16 + quad * 4 + reg;
          const int k = kt * 64 + wn + jj * 16 + l16;
          WfS[n][k] = f2bf(facc[ii][jj][reg]);
        }
  }
  __syncthreads();   // WfS + bfS ready

  // Main: C_tile = A(m0:64, 0:128) @ Wf^T + bfS
  f32x4 acc[2][2] = {};
  for (int kc = 0; kc < EDGE_DIM; kc += 32) {
    __syncthreads();
    {
      const float* p = A + (size_t)(m0 + r) * EDGE_DIM + kc + kg * 8;
      float4 a0 = *(const float4*)p, a1 = *(const float4*)(p + 4);
      *(short8*)&As2[r * 40 + kg * 8] = cvt8(a0, a1);
    }
    __syncthreads();
    short8 af0 = *(const short8*)&As2[(wm + l16) * 40 + quad * 8];
    short8 af1 = *(const short8*)&As2[(wm + 16 + l16) * 40 + quad * 8];
    short8 bf0 = *(const short8*)&WfS[wn + l16][kc + quad * 8];
    short8 bf1 = *(const short8*)&WfS[wn + 16 + l16][kc + quad * 8];
    acc[0][0] = __builtin_amdgcn_mfma_f32_16x16x32_bf16(af0, bf0, acc[0][0], 0, 0, 0);
    acc[0][1] = __builtin_amdgcn_mfma_f32_16x16x32_bf16(af0, bf1, acc[0][1], 0, 0, 0);
    acc[1][0] = __builtin_amdgcn_mfma_f32_16x16x32_bf16(af1, bf0, acc[1][0], 0, 0, 0);
    acc[1][1] = __builtin_amdgcn_mfma_f32_16x16x32_bf16(af1, bf1, acc[1][1], 0, 0, 0);
  }
#pragma unroll
  for (int j = 0; j < 2; ++j) {
    const int coln = wn + j * 16 + l16;
    const float bj = bfS[coln];
#pragma unroll
    for (int i = 0; i < 2; ++i)
#pragma unroll
      for (int reg = 0; reg < 4; ++reg) {
        const int row = m0 + wm + i * 16 + quad * 4 + reg;
        C[(size_t)row * HIDDEN + n0 + coln] = f2bf(acc[i][j][reg] + bj);
      }
  }
}

// Launch 1: z=0 Qh = query@wq.T+bq  +  out init (query + b_out)  + segStart;
//           z=1 Kh = key@(wk@w_edge).T + fused bias;
//           z=2 Vh = value@(wv@w_edge).T + fused bias.
__global__ __launch_bounds__(256) void proj(const float* __restrict__ query,
                                            const float* __restrict__ key,
                                            const float* __restrict__ value,
                                            const float* __restrict__ w_in,
                                            const float* __restrict__ b_in,
                                            const float* __restrict__ w_edge,
                                            const float* __restrict__ b_edge,
                                            const float* __restrict__ b_out,
                                            const int* __restrict__ gidx,
                                            unsigned short* Qh, unsigned short* Kh,
                                            unsigned short* Vh, int* segStart,
                                            float* __restrict__ out) {
  if (blockIdx.z == 0) {
    if (blockIdx.x == 0 && blockIdx.y == 0 && threadIdx.x <= NUM_GRAPHS)
      segStart[threadIdx.x] = lbound(gidx, N_EDGES, threadIdx.x);
    gemm_core(query, w_in, b_in, Qh, 256);
    // out init: out = query + b_out (attn blocks atomically add the rest)
    const int t = threadIdx.x, m0 = blockIdx.x * 64, n0 = blockIdx.y * 64;
#pragma unroll
    for (int i = 0; i < 4; ++i) {
      const int idx = t + i * 256;
      const int rr = idx >> 4, cc = (idx & 15) * 4;
      float4 q = *(const float4*)&query[(size_t)(m0 + rr) * HIDDEN + n0 + cc];
      float4 b = *(const float4*)&b_out[n0 + cc];
      q.x += b.x; q.y += b.y; q.z += b.z; q.w += b.w;
      *(float4*)&out[(size_t)(m0 + rr) * HIDDEN + n0 + cc] = q;
    }
  } else if (blockIdx.z == 1) {
    fused_kv_core(key, w_in + 256 * HIDDEN, b_in + 256, w_edge, b_edge, Kh);
  } else {
    fused_kv_core(value, w_in + 512 * HIDDEN, b_in + 512, w_edge, b_edge, Vh);
  }
}

// Launch 2: segment attention + fused out-projection.
// Grid (graph, head, zg=8); 16-row chunks; 4 waves x 4 rows; no online max
// (scores are 0.02-scale). Each chunk finishes with a 16x64 @ 64x256 MFMA
// out-proj partial, atomicAdd'ed into out (4 adds/element, one per head).
__global__ __launch_bounds__(256) void attn_segment(const unsigned short* __restrict__ Qh,
                                                    const unsigned short* __restrict__ Kh,
                                                    const unsigned short* __restrict__ Vh,
                                                    const int* __restrict__ segStart,
                                                    const float* __restrict__ w_out,
                                                    float* __restrict__ out) {
  const int graph = blockIdx.x, h = blockIdx.y, zg = blockIdx.z;
  const int segLo = segStart[graph];
  const int segHi = segStart[graph + 1];
  const int segLen = segHi - segLo;
  const int t = threadIdx.x, lane = t & 63, w = t >> 6;
  const int quad = lane >> 4, l16 = lane & 15;
  __shared__ float Qs[16][68], Ks[64][68], Vs[64][68];
  __shared__ float Ps[4][64][4];
  __shared__ unsigned short aohS[16][72];
  const float scale = 0.125f;           // 1/sqrt(64)
  const int r0 = w * 4;

  for (int chunk = zg; chunk * 16 < segLen; chunk += 8) {
    const int row0 = segLo + chunk * 16;
    const int rows = min(16, segHi - row0);
    __syncthreads();                    // prev chunk fully consumed
    { int r = t >> 4, d4 = (t & 15) * 4;
      if (r < rows)
        *(float4*)&Qs[r][d4] =
            us4f(*(const ushort4*)(Qh + (size_t)(row0 + r) * HIDDEN + h * DH + d4)); }

    float accv[4] = {0.f, 0.f, 0.f, 0.f}, lsum[4] = {0.f, 0.f, 0.f, 0.f};

    for (int c0 = segLo; c0 < segHi; c0 += 64) {
      const int tc = min(64, segHi - c0);
      __syncthreads();                  // Qs staged / prev tile reads done
#pragma unroll
      for (int it = 0; it < 4; ++it) {
        int s = t + it * 256; int j = s >> 4; int d4 = (s & 15) * 4;
        if (j < tc) {
          *(float4*)&Ks[j][d4] =
              us4f(*(const ushort4*)(Kh + (size_t)(c0 + j) * HIDDEN + h * DH + d4));
          *(float4*)&Vs[j][d4] =
              us4f(*(const ushort4*)(Vh + (size_t)(c0 + j) * HIDDEN + h * DH + d4));
        }
      }
      __syncthreads();
      float4 kreg[16];
#pragma unroll
      for (int d4 = 0; d4 < 16; ++d4) kreg[d4] = *(const float4*)&Ks[lane][d4 * 4];
      float p[4];
#pragma unroll
      for (int r = 0; r < 4; ++r) {
        float s = 0.f;
#pragma unroll
        for (int d4 = 0; d4 < 16; ++d4) {
          float4 q = *(const float4*)&Qs[r0 + r][d4 * 4];
          s += q.x * kreg[d4].x + q.y * kreg[d4].y + q.z * kreg[d4].z + q.w * kreg[d4].w;
        }
        p[r] = (lane < tc && r0 + r < rows) ? __expf(s * scale) : 0.f;
        lsum[r] += p[r];
      }
      float4 p4; p4.x = p[0]; p4.y = p[1]; p4.z = p[2]; p4.w = p[3];
      *(float4*)&Ps[w][lane][0] = p4;
      __asm__ volatile("s_waitcnt lgkmcnt(0)" ::: "memory");  // wave-private RAW
      for (int j = 0; j < tc; ++j) {
        const float v = Vs[j][lane];
        float4 pj = *(const float4*)&Ps[w][j][0];
        accv[0] += pj.x * v; accv[1] += pj.y * v;
        accv[2] += pj.z * v; accv[3] += pj.w * v;
      }
    }
#pragma unroll
    for (int off = 32; off; off >>= 1)
#pragma unroll
      for (int r = 0; r < 4; ++r) lsum[r] += __shfl_xor(lsum[r], off);

    // normalized attn output -> LDS (16 rows x 64 dh, bf16)
#pragma unroll
    for (int r = 0; r < 4; ++r)
      aohS[r0 + r][lane] = (r0 + r < rows) ? f2bf(accv[r] / lsum[r]) : (unsigned short)0;
    __syncthreads();

    // fused out-proj partial: [16 x 64] @ w_out[:, h*64:(h+1)*64]^T -> [16 x 256]
    // wave w handles out cols [w*64, w*64+64)
    f32x4 po[4] = {};
#pragma unroll
    for (int kc = 0; kc < DH; kc += 32) {
      short8 af = *(const short8*)&aohS[l16][kc + quad * 8];
#pragma unroll
      for (int nt = 0; nt < 4; ++nt) {
        const int n = w * 64 + nt * 16 + l16;
        const float* p = w_out + (size_t)n * HIDDEN + h * DH + kc + quad * 8;
        float4 b0 = *(const float4*)p, b1 = *(const float4*)(p + 4);
        po[nt] = __builtin_amdgcn_mfma_f32_16x16x32_bf16(af, cvt8(b0, b1), po[nt], 0, 0, 0);
      }
    }
#pragma unroll
    for (int nt = 0; nt < 4; ++nt)
#pragma unroll
      for (int reg = 0; reg < 4; ++reg) {
        const int rr = quad * 4 + reg;
        if (rr < rows)
          atomicAdd(&out[(size_t)(row0 + rr) * HIDDEN + w * 64 + nt * 16 + l16],
                    po[nt][reg]);
      }
  }
}

extern "C" void kernel_launch(void* const* d_in, const int* in_sizes, int n_in,
                              void* d_out, int out_size, void* d_ws, size_t ws_size,
                              hipStream_t stream) {
  const float* query  = (const float*)d_in[0];
  const float* key    = (const float*)d_in[1];
  const float* value  = (const float*)d_in[2];
  const int*   gidx   = (const int*)d_in[3];
  const float* w_edge = (const float*)d_in[4];
  const float* b_edge = (const float*)d_in[5];
  const float* w_in   = (const float*)d_in[6];
  const float* b_in   = (const float*)d_in[7];
  const float* w_out  = (const float*)d_in[8];
  const float* b_out  = (const float*)d_in[9];
  float* out = (float*)d_out;

  // workspace layout
  int* segStart = (int*)d_ws;                              // 128 ints
  unsigned short* Qh = (unsigned short*)((char*)d_ws + 512);
  unsigned short* Kh = Qh + (size_t)N_EDGES * HIDDEN;
  unsigned short* Vh = Kh + (size_t)N_EDGES * HIDDEN;
  // total ~6 MiB

  proj<<<dim3(64, 4, 3), 256, 0, stream>>>(query, key, value, w_in, b_in,
                                           w_edge, b_edge, b_out, gidx,
                                           Qh, Kh, Vh, segStart, out);
  attn_segment<<<dim3(NUM_GRAPHS, NUM_HEADS, 8), 256, 0, stream>>>(Qh, Kh, Vh, segStart,
                                                                   w_out, out);
}